// Round 5
// baseline (9428.585 us; speedup 1.0000x reference)
//
#include <hip/hip_runtime.h>
#include <hip/hip_bf16.h>
#include <math.h>

// Problem constants
#define BSZ 64
#define TT  512
#define DD  512
#define UU  512
#define NZ  2048   // 4*U

#define NSL    32    // u-slices (= blocks)
#define USL    16    // units per slice
#define KSTEPS 16    // 512 / 32 (MFMA k=32)

using short8  = __attribute__((ext_vector_type(8))) short;
using floatx4 = __attribute__((ext_vector_type(4))) float;
typedef unsigned long long u64;

// ---------------------------------------------------------------------------
// Phase 1: zx = x @ Wk.  M=32768, K=512, N=2048. fp32 tiled GEMM (unchanged).
// ---------------------------------------------------------------------------
template <bool ZXBF16>
__global__ __launch_bounds__(256) void gemm_zx(const float* __restrict__ A,
                                               const float* __restrict__ B,
                                               void* __restrict__ Cout) {
  __shared__ float As[16][65];
  __shared__ float Bs[16][64];

  const int tid = threadIdx.x;
  const int tx = tid & 15;
  const int ty = tid >> 4;
  const int m0 = blockIdx.y * 64;
  const int n0 = blockIdx.x * 64;

  const int lm  = tid >> 2;
  const int lk4 = (tid & 3) * 4;
  const int lk  = tid >> 4;
  const int ln4 = (tid & 15) * 4;

  float acc[4][4] = {};

  for (int k0 = 0; k0 < DD; k0 += 16) {
    float4 av = *(const float4*)(A + (size_t)(m0 + lm) * DD + k0 + lk4);
    float4 bv = *(const float4*)(B + (size_t)(k0 + lk) * NZ + n0 + ln4);
    As[lk4 + 0][lm] = av.x;
    As[lk4 + 1][lm] = av.y;
    As[lk4 + 2][lm] = av.z;
    As[lk4 + 3][lm] = av.w;
    *(float4*)&Bs[lk][ln4] = bv;
    __syncthreads();
#pragma unroll
    for (int kk = 0; kk < 16; ++kk) {
      float a[4], b[4];
#pragma unroll
      for (int i = 0; i < 4; ++i) a[i] = As[kk][ty * 4 + i];
#pragma unroll
      for (int j = 0; j < 4; ++j) b[j] = Bs[kk][tx * 4 + j];
#pragma unroll
      for (int i = 0; i < 4; ++i)
#pragma unroll
        for (int j = 0; j < 4; ++j) acc[i][j] = fmaf(a[i], b[j], acc[i][j]);
    }
    __syncthreads();
  }

#pragma unroll
  for (int i = 0; i < 4; ++i) {
    const size_t row = (size_t)(m0 + ty * 4 + i) * NZ + n0 + tx * 4;
    if constexpr (ZXBF16) {
      __hip_bfloat16* C = (__hip_bfloat16*)Cout;
#pragma unroll
      for (int j = 0; j < 4; ++j) C[row + j] = __float2bfloat16(acc[i][j]);
    } else {
      float* C = (float*)Cout;
      *(float4*)&C[row] = make_float4(acc[i][0], acc[i][1], acc[i][2], acc[i][3]);
    }
  }
}

// ---------------------------------------------------------------------------
// Phase 2: ONE persistent kernel, 32 blocks x 512 threads (1 CU each).
// Block sl owns units [16*sl, 16*sl+16) x 4 gates for ALL 64 batches.
// Wr slice resident in LDS (split-bf16 hi/lo, MFMA B-frag order, 128 KiB).
// h planes (hi/lo bf16) exchanged through ws via agent-scope RELAXED atomics
// on BOTH sides (no per-step acquire fence / buffer_inv -> zx stays cached).
// Flag release: h-stores drain at the post-epilogue __syncthreads (vmcnt(0)
// before s_barrier), then tid0 stores the flag.
// NOTE (R4 bug): each MFMA K-step covers 32 ushorts = 8 u64 -> A-frag
// addresses advance by K*8 u64 (K*4 was the R4 correctness bug).
// 32 blocks <= 256 CUs: all co-resident, no deadlock.
// ---------------------------------------------------------------------------
__device__ __forceinline__ floatx4 mfma16(short8 a, short8 b, floatx4 c) {
  return __builtin_amdgcn_mfma_f32_16x16x32_bf16(a, b, c, 0, 0, 0);
}

union frag_u {
  short8 v;
  u64 q[2];
};

template <bool ZXBF16>
__global__ __launch_bounds__(512) void lstm_persist(
    const void* __restrict__ zx_, const float* __restrict__ Wr,
    const float* __restrict__ bias, unsigned short* __restrict__ h_hi,
    unsigned short* __restrict__ h_lo, int* __restrict__ flags,
    float* __restrict__ out) {
  extern __shared__ char lds[];
  unsigned short* wr_hi = (unsigned short*)lds;            // [K][g][lane][8]
  unsigned short* wr_lo = wr_hi + KSTEPS * 4 * 64 * 8;     // 32768 ushorts each
  float* z_ex = (float*)(wr_lo + KSTEPS * 4 * 64 * 8);     // [4 g][64 b][16 u]

  const int sl = blockIdx.x;
  const int tid = threadIdx.x;
  const int wave = tid >> 6;          // 0..7
  const int lane = tid & 63;
  const int u0 = sl * USL;

  // ---- one-time: preformat Wr slice into LDS (split bf16, B-frag order) ----
  {
    const int cidx = tid & 63;        // g*16+u within slice
    const int koff = tid >> 6;        // 0..7
    const int g = cidx >> 4, u = cidx & 15;
    const int col = g * UU + u0 + u;
    for (int k0 = 0; k0 < DD; k0 += 8) {
      const int k = k0 + koff;
      const float v = Wr[(size_t)k * NZ + col];
      const __hip_bfloat16 vh = __float2bfloat16(v);
      const float rem = v - __bfloat162float(vh);
      const __hip_bfloat16 vl = __float2bfloat16(rem);
      const int K = k >> 5, kg = (k >> 3) & 3, j = k & 7;
      const int off = ((K * 4 + g) * 64 + (kg * 16 + u)) * 8 + j;
      wr_hi[off] = *(const unsigned short*)&vh;
      wr_lo[off] = *(const unsigned short*)&vl;
    }
  }
  __syncthreads();

  // MFMA wave mapping: mt = wave>>1 (batch tile), gates {gp, gp+1}
  const int mt = wave >> 1;
  const int gp = (wave & 1) * 2;
  const int am = lane & 15, akg = lane >> 4;
  const size_t arow = (size_t)(mt * 16 + am) * UU + akg * 8;  // ushort idx, 16B-aligned

  // epilogue mapping: thread -> (b, unit pair)
  const int eb = tid >> 3;            // 0..63
  const int up = tid & 7;             // unit pair 0..7 -> units 2up, 2up+1
  const float2 bias_i = *(const float2*)(bias + 0 * UU + u0 + 2 * up);
  const float2 bias_f = *(const float2*)(bias + 1 * UU + u0 + 2 * up);
  const float2 bias_g = *(const float2*)(bias + 2 * UU + u0 + 2 * up);
  const float2 bias_o = *(const float2*)(bias + 3 * UU + u0 + 2 * up);
  float c0 = 0.f, c1 = 0.f;
  const size_t plane_t = (size_t)BSZ * UU;          // 32768 ushorts / timestep
  const int wword = eb * (UU / 2) + (u0 >> 1) + up; // packed word idx in plane

  for (int t = 0; t < TT; ++t) {
    // ---- zx prefetch for this step (independent of h_t) ----
    float2 zi, zf, zg, zo;
    {
      const size_t zb = ((size_t)eb * TT + t) * NZ + u0 + 2 * up;
      if constexpr (ZXBF16) {
        const unsigned short* zx = (const unsigned short*)zx_;
        ushort2 vi = *(const ushort2*)(zx + zb + 0 * UU);
        ushort2 vf = *(const ushort2*)(zx + zb + 1 * UU);
        ushort2 vg = *(const ushort2*)(zx + zb + 2 * UU);
        ushort2 vo = *(const ushort2*)(zx + zb + 3 * UU);
        zi = make_float2(__bfloat162float(*(__hip_bfloat16*)&vi.x),
                         __bfloat162float(*(__hip_bfloat16*)&vi.y));
        zf = make_float2(__bfloat162float(*(__hip_bfloat16*)&vf.x),
                         __bfloat162float(*(__hip_bfloat16*)&vf.y));
        zg = make_float2(__bfloat162float(*(__hip_bfloat16*)&vg.x),
                         __bfloat162float(*(__hip_bfloat16*)&vg.y));
        zo = make_float2(__bfloat162float(*(__hip_bfloat16*)&vo.x),
                         __bfloat162float(*(__hip_bfloat16*)&vo.y));
      } else {
        const float* zx = (const float*)zx_;
        const float* p = zx + zb;
        zi = *(const float2*)(p + 0 * UU);
        zf = *(const float2*)(p + 1 * UU);
        zg = *(const float2*)(p + 2 * UU);
        zo = *(const float2*)(p + 3 * UU);
      }
    }

    // ---- acquire h_t: relaxed poll (no fence, no cache invalidation) ----
    if (tid < NSL) {
      const int* fp = flags + tid * 16;
      while (__hip_atomic_load(fp, __ATOMIC_RELAXED, __HIP_MEMORY_SCOPE_AGENT) < t) {
      }
    }
    __syncthreads();

    // ---- z for (mt, gp..gp+1): h loaded via relaxed agent atomic b64 ----
    const u64* Ahi = (const u64*)(h_hi + (size_t)t * plane_t + arow);
    const u64* Alo = (const u64*)(h_lo + (size_t)t * plane_t + arow);
    floatx4 a0g0 = {0, 0, 0, 0}, a1g0 = {0, 0, 0, 0}, a2g0 = {0, 0, 0, 0};
    floatx4 a0g1 = {0, 0, 0, 0}, a1g1 = {0, 0, 0, 0}, a2g1 = {0, 0, 0, 0};
#pragma unroll 4
    for (int K = 0; K < KSTEPS; ++K) {
      frag_u ahi, alo;
      // K-step covers 32 ushorts = 8 u64 (K*8, NOT K*4 — the R4 bug)
      ahi.q[0] = __hip_atomic_load(Ahi + K * 8 + 0, __ATOMIC_RELAXED,
                                   __HIP_MEMORY_SCOPE_AGENT);
      ahi.q[1] = __hip_atomic_load(Ahi + K * 8 + 1, __ATOMIC_RELAXED,
                                   __HIP_MEMORY_SCOPE_AGENT);
      alo.q[0] = __hip_atomic_load(Alo + K * 8 + 0, __ATOMIC_RELAXED,
                                   __HIP_MEMORY_SCOPE_AGENT);
      alo.q[1] = __hip_atomic_load(Alo + K * 8 + 1, __ATOMIC_RELAXED,
                                   __HIP_MEMORY_SCOPE_AGENT);
      const short8 bhi0 = *(const short8*)(wr_hi + ((K * 4 + gp) * 64 + lane) * 8);
      const short8 blo0 = *(const short8*)(wr_lo + ((K * 4 + gp) * 64 + lane) * 8);
      const short8 bhi1 = *(const short8*)(wr_hi + ((K * 4 + gp + 1) * 64 + lane) * 8);
      const short8 blo1 = *(const short8*)(wr_lo + ((K * 4 + gp + 1) * 64 + lane) * 8);
      a0g0 = mfma16(ahi.v, bhi0, a0g0);
      a1g0 = mfma16(ahi.v, blo0, a1g0);
      a2g0 = mfma16(alo.v, bhi0, a2g0);
      a0g1 = mfma16(ahi.v, bhi1, a0g1);
      a1g1 = mfma16(ahi.v, blo1, a1g1);
      a2g1 = mfma16(alo.v, bhi1, a2g1);
    }
    // C layout: u = lane&15, b-in-tile = (lane>>4)*4 + r
#pragma unroll
    for (int r = 0; r < 4; ++r) {
      const int bb = mt * 16 + (lane >> 4) * 4 + r;
      z_ex[((gp + 0) * 64 + bb) * 16 + (lane & 15)] = a0g0[r] + a1g0[r] + a2g0[r];
      z_ex[((gp + 1) * 64 + bb) * 16 + (lane & 15)] = a0g1[r] + a1g1[r] + a2g1[r];
    }
    __syncthreads();

    // ---- pointwise gates: thread = (eb, units 2up, 2up+1) ----
    const float2 ri = *(const float2*)&z_ex[(0 * 64 + eb) * 16 + 2 * up];
    const float2 rf = *(const float2*)&z_ex[(1 * 64 + eb) * 16 + 2 * up];
    const float2 rg = *(const float2*)&z_ex[(2 * 64 + eb) * 16 + 2 * up];
    const float2 ro = *(const float2*)&z_ex[(3 * 64 + eb) * 16 + 2 * up];

    const float i0 = 1.f / (1.f + expf(-(zi.x + ri.x + bias_i.x)));
    const float i1 = 1.f / (1.f + expf(-(zi.y + ri.y + bias_i.y)));
    const float f0 = 1.f / (1.f + expf(-(zf.x + rf.x + bias_f.x)));
    const float f1 = 1.f / (1.f + expf(-(zf.y + rf.y + bias_f.y)));
    const float g0 = tanhf(zg.x + rg.x + bias_g.x);
    const float g1 = tanhf(zg.y + rg.y + bias_g.y);
    const float o0 = 1.f / (1.f + expf(-(zo.x + ro.x + bias_o.x)));
    const float o1 = 1.f / (1.f + expf(-(zo.y + ro.y + bias_o.y)));
    c0 = f0 * c0 + i0 * g0;
    c1 = f1 * c1 + i1 * g1;
    const float h0 = o0 * tanhf(c0);
    const float h1 = o1 * tanhf(c1);

    // split-bf16 publish (packed pair words, agent-scope relaxed)
    const __hip_bfloat16 h0h = __float2bfloat16(h0);
    const __hip_bfloat16 h1h = __float2bfloat16(h1);
    const __hip_bfloat16 h0l = __float2bfloat16(h0 - __bfloat162float(h0h));
    const __hip_bfloat16 h1l = __float2bfloat16(h1 - __bfloat162float(h1h));
    const unsigned int whi =
        (unsigned int)*(const unsigned short*)&h0h |
        ((unsigned int)*(const unsigned short*)&h1h << 16);
    const unsigned int wlo =
        (unsigned int)*(const unsigned short*)&h0l |
        ((unsigned int)*(const unsigned short*)&h1l << 16);
    unsigned int* phi = (unsigned int*)(h_hi + (size_t)(t + 1) * plane_t) + wword;
    unsigned int* plo = (unsigned int*)(h_lo + (size_t)(t + 1) * plane_t) + wword;
    __hip_atomic_store(phi, whi, __ATOMIC_RELAXED, __HIP_MEMORY_SCOPE_AGENT);
    __hip_atomic_store(plo, wlo, __ATOMIC_RELAXED, __HIP_MEMORY_SCOPE_AGENT);

    if (t == TT - 1) {
      out[(size_t)eb * UU + u0 + 2 * up + 0] = h0;
      out[(size_t)eb * UU + u0 + 2 * up + 1] = h1;
    }

    // ---- release: barrier drains vmcnt (stores at coherence point) ----
    __syncthreads();
    if (tid == 0)
      __hip_atomic_store(flags + sl * 16, t + 1, __ATOMIC_RELAXED,
                         __HIP_MEMORY_SCOPE_AGENT);
  }
}

// ---------------------------------------------------------------------------
extern "C" void kernel_launch(void* const* d_in, const int* in_sizes, int n_in,
                              void* d_out, int out_size, void* d_ws, size_t ws_size,
                              hipStream_t stream) {
  const float* x    = (const float*)d_in[0];
  const float* Wk   = (const float*)d_in[1];
  const float* Wr   = (const float*)d_in[2];
  const float* bias = (const float*)d_in[3];
  float* out = (float*)d_out;

  const size_t plane_t = (size_t)BSZ * UU;                      // 32768
  const size_t hplane_bytes = (size_t)(TT + 1) * plane_t * 2;   // 32.06 MiB
  const size_t flags_bytes = (size_t)NSL * 16 * 4;              // 2 KiB
  const size_t zx_f32_bytes = (size_t)BSZ * TT * NZ * 4;        // 256 MiB

  const size_t need_f32 = zx_f32_bytes + 2 * hplane_bytes + flags_bytes;
  const bool use_bf16_zx = (ws_size < need_f32);
  const size_t zx_bytes = use_bf16_zx ? zx_f32_bytes / 2 : zx_f32_bytes;

  char* ws = (char*)d_ws;
  void* zx = (void*)ws;
  unsigned short* h_hi = (unsigned short*)(ws + zx_bytes);
  unsigned short* h_lo = (unsigned short*)(ws + zx_bytes + hplane_bytes);
  int* flags = (int*)(ws + zx_bytes + 2 * hplane_bytes);

  hipMemsetAsync(h_hi, 0, plane_t * 2, stream);  // h_0 slab
  hipMemsetAsync(h_lo, 0, plane_t * 2, stream);
  hipMemsetAsync(flags, 0, flags_bytes, stream);

  dim3 ggrid(NZ / 64, (BSZ * TT) / 64);
  if (use_bf16_zx)
    gemm_zx<true><<<ggrid, 256, 0, stream>>>(x, Wk, zx);
  else
    gemm_zx<false><<<ggrid, 256, 0, stream>>>(x, Wk, zx);

  const int lds_bytes = KSTEPS * 4 * 64 * 8 * 2 * 2 + 4 * 64 * 16 * 4;  // 147456
  if (use_bf16_zx) {
    hipFuncSetAttribute(reinterpret_cast<const void*>(lstm_persist<true>),
                        hipFuncAttributeMaxDynamicSharedMemorySize, lds_bytes);
    lstm_persist<true><<<NSL, 512, lds_bytes, stream>>>(zx, Wr, bias, h_hi, h_lo,
                                                        flags, out);
  } else {
    hipFuncSetAttribute(reinterpret_cast<const void*>(lstm_persist<false>),
                        hipFuncAttributeMaxDynamicSharedMemorySize, lds_bytes);
    lstm_persist<false><<<NSL, 512, lds_bytes, stream>>>(zx, Wr, bias, h_hi, h_lo,
                                                         flags, out);
  }
}

// Round 6
// 6106.819 us; speedup vs baseline: 1.5439x; 1.5439x over previous
//
#include <hip/hip_runtime.h>
#include <hip/hip_bf16.h>
#include <math.h>

// Problem constants
#define BSZ 64
#define TT  512
#define DD  512
#define UU  512
#define NZ  2048   // 4*U

#define NSL    32    // u-slices (= blocks)
#define USL    16    // units per slice
#define KSTEPS 16    // 512 / 32 (MFMA k=32)

using short8  = __attribute__((ext_vector_type(8))) short;
using floatx4 = __attribute__((ext_vector_type(4))) float;
typedef unsigned long long u64;

// ---------------------------------------------------------------------------
// Phase 1: zx = x @ Wk.  M=32768, K=512, N=2048. fp32 tiled GEMM (unchanged).
// ---------------------------------------------------------------------------
template <bool ZXBF16>
__global__ __launch_bounds__(256) void gemm_zx(const float* __restrict__ A,
                                               const float* __restrict__ B,
                                               void* __restrict__ Cout) {
  __shared__ float As[16][65];
  __shared__ float Bs[16][64];

  const int tid = threadIdx.x;
  const int tx = tid & 15;
  const int ty = tid >> 4;
  const int m0 = blockIdx.y * 64;
  const int n0 = blockIdx.x * 64;

  const int lm  = tid >> 2;
  const int lk4 = (tid & 3) * 4;
  const int lk  = tid >> 4;
  const int ln4 = (tid & 15) * 4;

  float acc[4][4] = {};

  for (int k0 = 0; k0 < DD; k0 += 16) {
    float4 av = *(const float4*)(A + (size_t)(m0 + lm) * DD + k0 + lk4);
    float4 bv = *(const float4*)(B + (size_t)(k0 + lk) * NZ + n0 + ln4);
    As[lk4 + 0][lm] = av.x;
    As[lk4 + 1][lm] = av.y;
    As[lk4 + 2][lm] = av.z;
    As[lk4 + 3][lm] = av.w;
    *(float4*)&Bs[lk][ln4] = bv;
    __syncthreads();
#pragma unroll
    for (int kk = 0; kk < 16; ++kk) {
      float a[4], b[4];
#pragma unroll
      for (int i = 0; i < 4; ++i) a[i] = As[kk][ty * 4 + i];
#pragma unroll
      for (int j = 0; j < 4; ++j) b[j] = Bs[kk][tx * 4 + j];
#pragma unroll
      for (int i = 0; i < 4; ++i)
#pragma unroll
        for (int j = 0; j < 4; ++j) acc[i][j] = fmaf(a[i], b[j], acc[i][j]);
    }
    __syncthreads();
  }

#pragma unroll
  for (int i = 0; i < 4; ++i) {
    const size_t row = (size_t)(m0 + ty * 4 + i) * NZ + n0 + tx * 4;
    if constexpr (ZXBF16) {
      __hip_bfloat16* C = (__hip_bfloat16*)Cout;
#pragma unroll
      for (int j = 0; j < 4; ++j) C[row + j] = __float2bfloat16(acc[i][j]);
    } else {
      float* C = (float*)Cout;
      *(float4*)&C[row] = make_float4(acc[i][0], acc[i][1], acc[i][2], acc[i][3]);
    }
  }
}

// ---------------------------------------------------------------------------
// Phase 2: ONE persistent kernel, 32 blocks x 512 threads (1 CU each).
// Block sl owns units [16*sl, 16*sl+16) x 4 gates for ALL 64 batches.
// Wr slice resident in LDS (split-bf16 hi/lo, MFMA B-frag order, 128 KiB).
//
// Exchange protocol (R6):
//   - h stores: packed 32-bit agent-scope RELAXED atomics (write-through to
//     the coherence point; drained by the vmcnt(0) at the post-epilogue
//     __syncthreads, then tid0 publishes the per-slice flag).
//   - flag polls: agent-scope RELAXED atomic loads (see remote stores).
//   - h loads: NORMAL b128 vector loads. Safe because each h-plane line is
//     written exactly once (unique address per timestep) and no reader
//     touches it before all 32 flags >= t, so no stale copy can exist in any
//     L1/L2 (dispatch-boundary acquire handles cross-replay state). A
//     workgroup-scope acquire fence (waitcnt only, NO buffer_inv) stops the
//     compiler from hoisting these loads above the spin loop.
// This avoids both R3's per-step L2 invalidate and R5's scalarized
// uncacheable atomic loads.
// 32 blocks <= 256 CUs: all co-resident, no deadlock.
// ---------------------------------------------------------------------------
__device__ __forceinline__ floatx4 mfma16(short8 a, short8 b, floatx4 c) {
  return __builtin_amdgcn_mfma_f32_16x16x32_bf16(a, b, c, 0, 0, 0);
}

template <bool ZXBF16>
__global__ __launch_bounds__(512) void lstm_persist(
    const void* __restrict__ zx_, const float* __restrict__ Wr,
    const float* __restrict__ bias, unsigned short* __restrict__ h_hi,
    unsigned short* __restrict__ h_lo, int* __restrict__ flags,
    float* __restrict__ out) {
  extern __shared__ char lds[];
  unsigned short* wr_hi = (unsigned short*)lds;            // [K][g][lane][8]
  unsigned short* wr_lo = wr_hi + KSTEPS * 4 * 64 * 8;     // 32768 ushorts each
  float* z_ex = (float*)(wr_lo + KSTEPS * 4 * 64 * 8);     // [4 g][64 b][16 u]

  const int sl = blockIdx.x;
  const int tid = threadIdx.x;
  const int wave = tid >> 6;          // 0..7
  const int lane = tid & 63;
  const int u0 = sl * USL;

  // ---- one-time: preformat Wr slice into LDS (split bf16, B-frag order) ----
  {
    const int cidx = tid & 63;        // g*16+u within slice
    const int koff = tid >> 6;        // 0..7
    const int g = cidx >> 4, u = cidx & 15;
    const int col = g * UU + u0 + u;
    for (int k0 = 0; k0 < DD; k0 += 8) {
      const int k = k0 + koff;
      const float v = Wr[(size_t)k * NZ + col];
      const __hip_bfloat16 vh = __float2bfloat16(v);
      const float rem = v - __bfloat162float(vh);
      const __hip_bfloat16 vl = __float2bfloat16(rem);
      const int K = k >> 5, kg = (k >> 3) & 3, j = k & 7;
      const int off = ((K * 4 + g) * 64 + (kg * 16 + u)) * 8 + j;
      wr_hi[off] = *(const unsigned short*)&vh;
      wr_lo[off] = *(const unsigned short*)&vl;
    }
  }
  __syncthreads();

  // MFMA wave mapping: mt = wave>>1 (batch tile), gates {gp, gp+1}
  const int mt = wave >> 1;
  const int gp = (wave & 1) * 2;
  const int am = lane & 15, akg = lane >> 4;
  const size_t arow = (size_t)(mt * 16 + am) * UU + akg * 8;  // ushort idx, 16B-aligned

  // epilogue mapping: thread -> (b, unit pair)
  const int eb = tid >> 3;            // 0..63
  const int up = tid & 7;             // unit pair 0..7 -> units 2up, 2up+1
  const float2 bias_i = *(const float2*)(bias + 0 * UU + u0 + 2 * up);
  const float2 bias_f = *(const float2*)(bias + 1 * UU + u0 + 2 * up);
  const float2 bias_g = *(const float2*)(bias + 2 * UU + u0 + 2 * up);
  const float2 bias_o = *(const float2*)(bias + 3 * UU + u0 + 2 * up);
  float c0 = 0.f, c1 = 0.f;
  const size_t plane_t = (size_t)BSZ * UU;          // 32768 ushorts / timestep
  const int wword = eb * (UU / 2) + (u0 >> 1) + up; // packed word idx in plane

  for (int t = 0; t < TT; ++t) {
    // ---- zx prefetch for this step (independent of h_t) ----
    float2 zi, zf, zg, zo;
    {
      const size_t zb = ((size_t)eb * TT + t) * NZ + u0 + 2 * up;
      if constexpr (ZXBF16) {
        const unsigned short* zx = (const unsigned short*)zx_;
        ushort2 vi = *(const ushort2*)(zx + zb + 0 * UU);
        ushort2 vf = *(const ushort2*)(zx + zb + 1 * UU);
        ushort2 vg = *(const ushort2*)(zx + zb + 2 * UU);
        ushort2 vo = *(const ushort2*)(zx + zb + 3 * UU);
        zi = make_float2(__bfloat162float(*(__hip_bfloat16*)&vi.x),
                         __bfloat162float(*(__hip_bfloat16*)&vi.y));
        zf = make_float2(__bfloat162float(*(__hip_bfloat16*)&vf.x),
                         __bfloat162float(*(__hip_bfloat16*)&vf.y));
        zg = make_float2(__bfloat162float(*(__hip_bfloat16*)&vg.x),
                         __bfloat162float(*(__hip_bfloat16*)&vg.y));
        zo = make_float2(__bfloat162float(*(__hip_bfloat16*)&vo.x),
                         __bfloat162float(*(__hip_bfloat16*)&vo.y));
      } else {
        const float* zx = (const float*)zx_;
        const float* p = zx + zb;
        zi = *(const float2*)(p + 0 * UU);
        zf = *(const float2*)(p + 1 * UU);
        zg = *(const float2*)(p + 2 * UU);
        zo = *(const float2*)(p + 3 * UU);
      }
    }

    // ---- acquire h_t: relaxed poll, then workgroup fence (no buffer_inv) ----
    if (tid < NSL) {
      const int* fp = flags + tid * 16;
      while (__hip_atomic_load(fp, __ATOMIC_RELAXED, __HIP_MEMORY_SCOPE_AGENT) < t) {
      }
    }
    __syncthreads();
    __builtin_amdgcn_fence(__ATOMIC_ACQUIRE, "workgroup");

    // ---- z for (mt, gp..gp+1): h via normal b128 loads (fresh-by-protocol) ----
    const unsigned short* Ahi = h_hi + (size_t)t * plane_t + arow;
    const unsigned short* Alo = h_lo + (size_t)t * plane_t + arow;
    floatx4 a0g0 = {0, 0, 0, 0}, a1g0 = {0, 0, 0, 0}, a2g0 = {0, 0, 0, 0};
    floatx4 a0g1 = {0, 0, 0, 0}, a1g1 = {0, 0, 0, 0}, a2g1 = {0, 0, 0, 0};
#pragma unroll 4
    for (int K = 0; K < KSTEPS; ++K) {
      const short8 ahi = *(const short8*)(Ahi + K * 32);
      const short8 alo = *(const short8*)(Alo + K * 32);
      const short8 bhi0 = *(const short8*)(wr_hi + ((K * 4 + gp) * 64 + lane) * 8);
      const short8 blo0 = *(const short8*)(wr_lo + ((K * 4 + gp) * 64 + lane) * 8);
      const short8 bhi1 = *(const short8*)(wr_hi + ((K * 4 + gp + 1) * 64 + lane) * 8);
      const short8 blo1 = *(const short8*)(wr_lo + ((K * 4 + gp + 1) * 64 + lane) * 8);
      a0g0 = mfma16(ahi, bhi0, a0g0);
      a1g0 = mfma16(ahi, blo0, a1g0);
      a2g0 = mfma16(alo, bhi0, a2g0);
      a0g1 = mfma16(ahi, bhi1, a0g1);
      a1g1 = mfma16(ahi, blo1, a1g1);
      a2g1 = mfma16(alo, bhi1, a2g1);
    }
    // C layout: u = lane&15, b-in-tile = (lane>>4)*4 + r
#pragma unroll
    for (int r = 0; r < 4; ++r) {
      const int bb = mt * 16 + (lane >> 4) * 4 + r;
      z_ex[((gp + 0) * 64 + bb) * 16 + (lane & 15)] = a0g0[r] + a1g0[r] + a2g0[r];
      z_ex[((gp + 1) * 64 + bb) * 16 + (lane & 15)] = a0g1[r] + a1g1[r] + a2g1[r];
    }
    __syncthreads();

    // ---- pointwise gates: thread = (eb, units 2up, 2up+1) ----
    const float2 ri = *(const float2*)&z_ex[(0 * 64 + eb) * 16 + 2 * up];
    const float2 rf = *(const float2*)&z_ex[(1 * 64 + eb) * 16 + 2 * up];
    const float2 rg = *(const float2*)&z_ex[(2 * 64 + eb) * 16 + 2 * up];
    const float2 ro = *(const float2*)&z_ex[(3 * 64 + eb) * 16 + 2 * up];

    const float i0 = 1.f / (1.f + expf(-(zi.x + ri.x + bias_i.x)));
    const float i1 = 1.f / (1.f + expf(-(zi.y + ri.y + bias_i.y)));
    const float f0 = 1.f / (1.f + expf(-(zf.x + rf.x + bias_f.x)));
    const float f1 = 1.f / (1.f + expf(-(zf.y + rf.y + bias_f.y)));
    const float g0 = tanhf(zg.x + rg.x + bias_g.x);
    const float g1 = tanhf(zg.y + rg.y + bias_g.y);
    const float o0 = 1.f / (1.f + expf(-(zo.x + ro.x + bias_o.x)));
    const float o1 = 1.f / (1.f + expf(-(zo.y + ro.y + bias_o.y)));
    c0 = f0 * c0 + i0 * g0;
    c1 = f1 * c1 + i1 * g1;
    const float h0 = o0 * tanhf(c0);
    const float h1 = o1 * tanhf(c1);

    // split-bf16 publish (packed pair words, agent-scope relaxed write-through)
    const __hip_bfloat16 h0h = __float2bfloat16(h0);
    const __hip_bfloat16 h1h = __float2bfloat16(h1);
    const __hip_bfloat16 h0l = __float2bfloat16(h0 - __bfloat162float(h0h));
    const __hip_bfloat16 h1l = __float2bfloat16(h1 - __bfloat162float(h1h));
    const unsigned int whi =
        (unsigned int)*(const unsigned short*)&h0h |
        ((unsigned int)*(const unsigned short*)&h1h << 16);
    const unsigned int wlo =
        (unsigned int)*(const unsigned short*)&h0l |
        ((unsigned int)*(const unsigned short*)&h1l << 16);
    unsigned int* phi = (unsigned int*)(h_hi + (size_t)(t + 1) * plane_t) + wword;
    unsigned int* plo = (unsigned int*)(h_lo + (size_t)(t + 1) * plane_t) + wword;
    __hip_atomic_store(phi, whi, __ATOMIC_RELAXED, __HIP_MEMORY_SCOPE_AGENT);
    __hip_atomic_store(plo, wlo, __ATOMIC_RELAXED, __HIP_MEMORY_SCOPE_AGENT);

    if (t == TT - 1) {
      out[(size_t)eb * UU + u0 + 2 * up + 0] = h0;
      out[(size_t)eb * UU + u0 + 2 * up + 1] = h1;
    }

    // ---- release: barrier drains vmcnt (stores at coherence point) ----
    __syncthreads();
    if (tid == 0)
      __hip_atomic_store(flags + sl * 16, t + 1, __ATOMIC_RELAXED,
                         __HIP_MEMORY_SCOPE_AGENT);
  }
}

// ---------------------------------------------------------------------------
extern "C" void kernel_launch(void* const* d_in, const int* in_sizes, int n_in,
                              void* d_out, int out_size, void* d_ws, size_t ws_size,
                              hipStream_t stream) {
  const float* x    = (const float*)d_in[0];
  const float* Wk   = (const float*)d_in[1];
  const float* Wr   = (const float*)d_in[2];
  const float* bias = (const float*)d_in[3];
  float* out = (float*)d_out;

  const size_t plane_t = (size_t)BSZ * UU;                      // 32768
  const size_t hplane_bytes = (size_t)(TT + 1) * plane_t * 2;   // 32.06 MiB
  const size_t flags_bytes = (size_t)NSL * 16 * 4;              // 2 KiB
  const size_t zx_f32_bytes = (size_t)BSZ * TT * NZ * 4;        // 256 MiB

  const size_t need_f32 = zx_f32_bytes + 2 * hplane_bytes + flags_bytes;
  const bool use_bf16_zx = (ws_size < need_f32);
  const size_t zx_bytes = use_bf16_zx ? zx_f32_bytes / 2 : zx_f32_bytes;

  char* ws = (char*)d_ws;
  void* zx = (void*)ws;
  unsigned short* h_hi = (unsigned short*)(ws + zx_bytes);
  unsigned short* h_lo = (unsigned short*)(ws + zx_bytes + hplane_bytes);
  int* flags = (int*)(ws + zx_bytes + 2 * hplane_bytes);

  hipMemsetAsync(h_hi, 0, plane_t * 2, stream);  // h_0 slab
  hipMemsetAsync(h_lo, 0, plane_t * 2, stream);
  hipMemsetAsync(flags, 0, flags_bytes, stream);

  dim3 ggrid(NZ / 64, (BSZ * TT) / 64);
  if (use_bf16_zx)
    gemm_zx<true><<<ggrid, 256, 0, stream>>>(x, Wk, zx);
  else
    gemm_zx<false><<<ggrid, 256, 0, stream>>>(x, Wk, zx);

  const int lds_bytes = KSTEPS * 4 * 64 * 8 * 2 * 2 + 4 * 64 * 16 * 4;  // 147456
  if (use_bf16_zx) {
    hipFuncSetAttribute(reinterpret_cast<const void*>(lstm_persist<true>),
                        hipFuncAttributeMaxDynamicSharedMemorySize, lds_bytes);
    lstm_persist<true><<<NSL, 512, lds_bytes, stream>>>(zx, Wr, bias, h_hi, h_lo,
                                                        flags, out);
  } else {
    hipFuncSetAttribute(reinterpret_cast<const void*>(lstm_persist<false>),
                        hipFuncAttributeMaxDynamicSharedMemorySize, lds_bytes);
    lstm_persist<false><<<NSL, 512, lds_bytes, stream>>>(zx, Wr, bias, h_hi, h_lo,
                                                         flags, out);
  }
}

// Round 7
// 4405.952 us; speedup vs baseline: 2.1400x; 1.3860x over previous
//
#include <hip/hip_runtime.h>
#include <hip/hip_bf16.h>
#include <math.h>

// Problem constants
#define BSZ 64
#define TT  512
#define DD  512
#define UU  512
#define NZ  2048   // 4*U

#define NSL    32    // u-slices
#define USL    16    // units per slice
#define NBG    4     // batch groups
#define BG     16    // batches per group (= MFMA m)
#define KSTEPS 16    // 512 / 32 (MFMA k=32)

using short8  = __attribute__((ext_vector_type(8))) short;
using floatx4 = __attribute__((ext_vector_type(4))) float;
typedef unsigned long long u64;

// ---------------------------------------------------------------------------
// Phase 1: zx = x @ Wk.  M=32768, K=512, N=2048. fp32 tiled GEMM (unchanged).
// ---------------------------------------------------------------------------
template <bool ZXBF16>
__global__ __launch_bounds__(256) void gemm_zx(const float* __restrict__ A,
                                               const float* __restrict__ B,
                                               void* __restrict__ Cout) {
  __shared__ float As[16][65];
  __shared__ float Bs[16][64];

  const int tid = threadIdx.x;
  const int tx = tid & 15;
  const int ty = tid >> 4;
  const int m0 = blockIdx.y * 64;
  const int n0 = blockIdx.x * 64;

  const int lm  = tid >> 2;
  const int lk4 = (tid & 3) * 4;
  const int lk  = tid >> 4;
  const int ln4 = (tid & 15) * 4;

  float acc[4][4] = {};

  for (int k0 = 0; k0 < DD; k0 += 16) {
    float4 av = *(const float4*)(A + (size_t)(m0 + lm) * DD + k0 + lk4);
    float4 bv = *(const float4*)(B + (size_t)(k0 + lk) * NZ + n0 + ln4);
    As[lk4 + 0][lm] = av.x;
    As[lk4 + 1][lm] = av.y;
    As[lk4 + 2][lm] = av.z;
    As[lk4 + 3][lm] = av.w;
    *(float4*)&Bs[lk][ln4] = bv;
    __syncthreads();
#pragma unroll
    for (int kk = 0; kk < 16; ++kk) {
      float a[4], b[4];
#pragma unroll
      for (int i = 0; i < 4; ++i) a[i] = As[kk][ty * 4 + i];
#pragma unroll
      for (int j = 0; j < 4; ++j) b[j] = Bs[kk][tx * 4 + j];
#pragma unroll
      for (int i = 0; i < 4; ++i)
#pragma unroll
        for (int j = 0; j < 4; ++j) acc[i][j] = fmaf(a[i], b[j], acc[i][j]);
    }
    __syncthreads();
  }

#pragma unroll
  for (int i = 0; i < 4; ++i) {
    const size_t row = (size_t)(m0 + ty * 4 + i) * NZ + n0 + tx * 4;
    if constexpr (ZXBF16) {
      __hip_bfloat16* C = (__hip_bfloat16*)Cout;
#pragma unroll
      for (int j = 0; j < 4; ++j) C[row + j] = __float2bfloat16(acc[i][j]);
    } else {
      float* C = (float*)Cout;
      *(float4*)&C[row] = make_float4(acc[i][0], acc[i][1], acc[i][2], acc[i][3]);
    }
  }
}

// ---------------------------------------------------------------------------
// Phase 2: ONE persistent kernel, (NSL=32 x NBG=4) = 128 blocks x 256 threads
// (4 waves = 4 gates), 1 block/CU (132 KiB LDS).
// Block (sl,bg): z[16 b of bg][16 u of sl][4 gates]; reads h only for its 16
// batches (32 KiB/step incl. hi/lo) -> 4x less critical-path read volume
// than R6's 32-block layout, spread over 4x more CUs.
//
// Exchange protocol (R6, proven): h stores = packed 32-bit agent-scope
// RELAXED atomics (write-through; drained by the vmcnt(0) at the
// post-epilogue __syncthreads, then tid0 publishes flags[bg][sl]). Readers
// poll their bg's 32 flags with RELAXED atomic loads, then a
// workgroup-scope acquire fence (waitcnt only, no buffer_inv) orders the
// normal b128 h loads. Safe: every h line is written exactly once per
// timestep address, never read before all its writers' flags publish, so no
// stale copy can exist in any cache.
// 128 blocks <= 256 CUs: all co-resident, no deadlock.
// ---------------------------------------------------------------------------
__device__ __forceinline__ floatx4 mfma16(short8 a, short8 b, floatx4 c) {
  return __builtin_amdgcn_mfma_f32_16x16x32_bf16(a, b, c, 0, 0, 0);
}

template <bool ZXBF16>
__global__ __launch_bounds__(256) void lstm_persist(
    const void* __restrict__ zx_, const float* __restrict__ Wr,
    const float* __restrict__ bias, unsigned short* __restrict__ h_hi,
    unsigned short* __restrict__ h_lo, int* __restrict__ flags,
    float* __restrict__ out) {
  extern __shared__ char lds[];
  unsigned short* wr_hi = (unsigned short*)lds;            // [K][g][lane][8]
  unsigned short* wr_lo = wr_hi + KSTEPS * 4 * 64 * 8;     // 32768 ushorts each
  float* z_ex = (float*)(wr_lo + KSTEPS * 4 * 64 * 8);     // [4 g][16 b][16 u]

  const int sl = blockIdx.x;          // u-slice 0..31
  const int bg = blockIdx.y;          // batch group 0..3
  const int tid = threadIdx.x;
  const int g = tid >> 6;             // wave = gate 0..3
  const int lane = tid & 63;
  const int u0 = sl * USL;

  // ---- one-time: preformat Wr slice into LDS (split bf16, B-frag order) ----
  {
    const int cidx = tid & 63;        // gg*16+u within slice
    const int koff = tid >> 6;        // 0..3
    const int gg = cidx >> 4, u = cidx & 15;
    const int col = gg * UU + u0 + u;
    for (int k0 = 0; k0 < DD; k0 += 4) {
      const int k = k0 + koff;
      const float v = Wr[(size_t)k * NZ + col];
      const __hip_bfloat16 vh = __float2bfloat16(v);
      const float rem = v - __bfloat162float(vh);
      const __hip_bfloat16 vl = __float2bfloat16(rem);
      const int K = k >> 5, kg = (k >> 3) & 3, j = k & 7;
      const int off = ((K * 4 + gg) * 64 + (kg * 16 + u)) * 8 + j;
      wr_hi[off] = *(const unsigned short*)&vh;
      wr_lo[off] = *(const unsigned short*)&vl;
    }
  }
  __syncthreads();

  // MFMA A-fragment addressing: m = bg*16 + (lane&15), kgroup = lane>>4
  const int am = lane & 15, akg = lane >> 4;
  const size_t arow = (size_t)(bg * BG + am) * UU + akg * 8;  // ushort idx

  // epilogue mapping: thread -> (local batch eb, unit eu)
  const int eb = tid >> 4;            // 0..15
  const int eu = tid & 15;            // 0..15
  const int b = bg * BG + eb;         // global batch
  const float bias_i = bias[0 * UU + u0 + eu];
  const float bias_f = bias[1 * UU + u0 + eu];
  const float bias_g = bias[2 * UU + u0 + eu];
  const float bias_o = bias[3 * UU + u0 + eu];
  float c_state = 0.f;
  const size_t plane_t = (size_t)BSZ * UU;          // 32768 ushorts / timestep
  // packed-pair word index for (b, eu even): (b*UU + u0 + eu)/2
  const int wword = (b * UU + u0 + eu) >> 1;

  int* myflag = flags + (bg * NSL + sl) * 16;

  for (int t = 0; t < TT; ++t) {
    // ---- zx prefetch for this step (independent of h_t) ----
    float zi, zf, zg, zo;
    {
      const size_t zb = ((size_t)b * TT + t) * NZ + u0 + eu;
      if constexpr (ZXBF16) {
        const unsigned short* zx = (const unsigned short*)zx_;
        zi = __bfloat162float(*(const __hip_bfloat16*)&zx[zb + 0 * UU]);
        zf = __bfloat162float(*(const __hip_bfloat16*)&zx[zb + 1 * UU]);
        zg = __bfloat162float(*(const __hip_bfloat16*)&zx[zb + 2 * UU]);
        zo = __bfloat162float(*(const __hip_bfloat16*)&zx[zb + 3 * UU]);
      } else {
        const float* zx = (const float*)zx_;
        zi = zx[zb + 0 * UU];
        zf = zx[zb + 1 * UU];
        zg = zx[zb + 2 * UU];
        zo = zx[zb + 3 * UU];
      }
    }

    // ---- acquire h_t: relaxed poll of this bg's 32 flags, then wg fence ----
    if (tid < NSL) {
      const int* fp = flags + (bg * NSL + tid) * 16;
      while (__hip_atomic_load(fp, __ATOMIC_RELAXED, __HIP_MEMORY_SCOPE_AGENT) < t) {
      }
    }
    __syncthreads();
    __builtin_amdgcn_fence(__ATOMIC_ACQUIRE, "workgroup");

    // ---- z[16b][16u] for gate g via split-bf16 MFMA ----
    const unsigned short* Ahi = h_hi + (size_t)t * plane_t + arow;
    const unsigned short* Alo = h_lo + (size_t)t * plane_t + arow;
    floatx4 a0 = {0, 0, 0, 0}, a1 = {0, 0, 0, 0}, a2 = {0, 0, 0, 0};
#pragma unroll 4
    for (int K = 0; K < KSTEPS; ++K) {
      const short8 ahi = *(const short8*)(Ahi + K * 32);
      const short8 alo = *(const short8*)(Alo + K * 32);
      const short8 bhi = *(const short8*)(wr_hi + ((K * 4 + g) * 64 + lane) * 8);
      const short8 blo = *(const short8*)(wr_lo + ((K * 4 + g) * 64 + lane) * 8);
      a0 = mfma16(ahi, bhi, a0);
      a1 = mfma16(ahi, blo, a1);
      a2 = mfma16(alo, bhi, a2);
    }
    // C layout: u = lane&15, b-in-tile = (lane>>4)*4 + r
#pragma unroll
    for (int r = 0; r < 4; ++r) {
      const int bb = (lane >> 4) * 4 + r;
      z_ex[(g * 16 + bb) * 16 + (lane & 15)] = a0[r] + a1[r] + a2[r];
    }
    __syncthreads();

    // ---- pointwise gates: thread = (eb, eu) ----
    zi += z_ex[(0 * 16 + eb) * 16 + eu] + bias_i;
    zf += z_ex[(1 * 16 + eb) * 16 + eu] + bias_f;
    zg += z_ex[(2 * 16 + eb) * 16 + eu] + bias_g;
    zo += z_ex[(3 * 16 + eb) * 16 + eu] + bias_o;

    const float ig = 1.f / (1.f + expf(-zi));
    const float fg = 1.f / (1.f + expf(-zf));
    const float gg = tanhf(zg);
    const float og = 1.f / (1.f + expf(-zo));
    c_state = fg * c_state + ig * gg;
    const float hn = og * tanhf(c_state);

    // split-bf16; pack pair-words via shfl, even threads store (32-bit atomics)
    const __hip_bfloat16 hh = __float2bfloat16(hn);
    const float hrem = hn - __bfloat162float(hh);
    const __hip_bfloat16 hl = __float2bfloat16(hrem);
    const unsigned int vhi = (unsigned int)*(const unsigned short*)&hh;
    const unsigned int vlo = (unsigned int)*(const unsigned short*)&hl;
    const unsigned int phi_n = (unsigned int)__shfl_xor((int)vhi, 1);
    const unsigned int plo_n = (unsigned int)__shfl_xor((int)vlo, 1);
    if ((tid & 1) == 0) {
      const unsigned int whi = vhi | (phi_n << 16);
      const unsigned int wlo = vlo | (plo_n << 16);
      unsigned int* phi = (unsigned int*)(h_hi + (size_t)(t + 1) * plane_t) + wword;
      unsigned int* plo = (unsigned int*)(h_lo + (size_t)(t + 1) * plane_t) + wword;
      __hip_atomic_store(phi, whi, __ATOMIC_RELAXED, __HIP_MEMORY_SCOPE_AGENT);
      __hip_atomic_store(plo, wlo, __ATOMIC_RELAXED, __HIP_MEMORY_SCOPE_AGENT);
    }

    if (t == TT - 1) out[(size_t)b * UU + u0 + eu] = hn;

    // ---- release: barrier drains vmcnt (stores at coherence point) ----
    __syncthreads();
    if (tid == 0)
      __hip_atomic_store(myflag, t + 1, __ATOMIC_RELAXED,
                         __HIP_MEMORY_SCOPE_AGENT);
  }
}

// ---------------------------------------------------------------------------
extern "C" void kernel_launch(void* const* d_in, const int* in_sizes, int n_in,
                              void* d_out, int out_size, void* d_ws, size_t ws_size,
                              hipStream_t stream) {
  const float* x    = (const float*)d_in[0];
  const float* Wk   = (const float*)d_in[1];
  const float* Wr   = (const float*)d_in[2];
  const float* bias = (const float*)d_in[3];
  float* out = (float*)d_out;

  const size_t plane_t = (size_t)BSZ * UU;                      // 32768
  const size_t hplane_bytes = (size_t)(TT + 1) * plane_t * 2;   // 32.06 MiB
  const size_t flags_bytes = (size_t)NBG * NSL * 16 * 4;        // 8 KiB
  const size_t zx_f32_bytes = (size_t)BSZ * TT * NZ * 4;        // 256 MiB

  const size_t need_f32 = zx_f32_bytes + 2 * hplane_bytes + flags_bytes;
  const bool use_bf16_zx = (ws_size < need_f32);
  const size_t zx_bytes = use_bf16_zx ? zx_f32_bytes / 2 : zx_f32_bytes;

  char* ws = (char*)d_ws;
  void* zx = (void*)ws;
  unsigned short* h_hi = (unsigned short*)(ws + zx_bytes);
  unsigned short* h_lo = (unsigned short*)(ws + zx_bytes + hplane_bytes);
  int* flags = (int*)(ws + zx_bytes + 2 * hplane_bytes);

  hipMemsetAsync(h_hi, 0, plane_t * 2, stream);  // h_0 slab
  hipMemsetAsync(h_lo, 0, plane_t * 2, stream);
  hipMemsetAsync(flags, 0, flags_bytes, stream);

  dim3 ggrid(NZ / 64, (BSZ * TT) / 64);
  if (use_bf16_zx)
    gemm_zx<true><<<ggrid, 256, 0, stream>>>(x, Wk, zx);
  else
    gemm_zx<false><<<ggrid, 256, 0, stream>>>(x, Wk, zx);

  const int lds_bytes = KSTEPS * 4 * 64 * 8 * 2 * 2 + 4 * 16 * 16 * 4;  // 135168
  dim3 pgrid(NSL, NBG);
  if (use_bf16_zx) {
    hipFuncSetAttribute(reinterpret_cast<const void*>(lstm_persist<true>),
                        hipFuncAttributeMaxDynamicSharedMemorySize, lds_bytes);
    lstm_persist<true><<<pgrid, 256, lds_bytes, stream>>>(zx, Wr, bias, h_hi, h_lo,
                                                          flags, out);
  } else {
    hipFuncSetAttribute(reinterpret_cast<const void*>(lstm_persist<false>),
                        hipFuncAttributeMaxDynamicSharedMemorySize, lds_bytes);
    lstm_persist<false><<<pgrid, 256, lds_bytes, stream>>>(zx, Wr, bias, h_hi, h_lo,
                                                           flags, out);
  }
}